// Round 1
// baseline (144.847 us; speedup 1.0000x reference)
//
#include <hip/hip_runtime.h>

#define B_  16
#define SQ_ 128
#define SV_ 128
#define DQ_ 512
#define DV_ 512
#define U_  256

typedef float f32x4 __attribute__((ext_vector_type(4)));
typedef short s16x4 __attribute__((ext_vector_type(4)));

__device__ __forceinline__ short f2bf(float f) {
  unsigned u = __float_as_uint(f);
  u += 0x7fffu + ((u >> 16) & 1u);   // RNE to bf16
  return (short)(u >> 16);
}

// ---- K1: s1 = Q@W1+b1 ; s2 = V@W2+b2  (bf16 MFMA 16x16x16_1k) ----
// X: [2048,512] fp32, W: [512,256] fp32, S: [2048,256] fp32
__global__ __launch_bounds__(256) void k_proj(
    const float* __restrict__ Q, const float* __restrict__ Vv,
    const float* __restrict__ W1, const float* __restrict__ b1,
    const float* __restrict__ W2, const float* __restrict__ b2,
    float* __restrict__ s1, float* __restrict__ s2)
{
  const int which = blockIdx.z;
  const float* __restrict__ X    = which ? Vv : Q;
  const float* __restrict__ W    = which ? W2 : W1;
  const float* __restrict__ bias = which ? b2 : b1;
  float* __restrict__ S          = which ? s2 : s1;

  const int lane  = threadIdx.x & 63;
  const int wid   = threadIdx.x >> 6;
  const int row16 = lane & 15;
  const int quad  = lane >> 4;

  const int m0 = blockIdx.x * 64 + (wid >> 1) * 32;  // wave: 32x32 tile
  const int n0 = blockIdx.y * 64 + (wid & 1) * 32;

  f32x4 acc[2][2];
  #pragma unroll
  for (int i = 0; i < 2; ++i)
    #pragma unroll
    for (int j = 0; j < 2; ++j)
      acc[i][j] = (f32x4){0.f, 0.f, 0.f, 0.f};

  for (int k0 = 0; k0 < DQ_; k0 += 16) {
    s16x4 af[2], bfr[2];
    #pragma unroll
    for (int mt = 0; mt < 2; ++mt) {
      f32x4 av = *(const f32x4*)&X[(m0 + mt * 16 + row16) * DQ_ + k0 + quad * 4];
      af[mt][0] = f2bf(av[0]); af[mt][1] = f2bf(av[1]);
      af[mt][2] = f2bf(av[2]); af[mt][3] = f2bf(av[3]);
    }
    #pragma unroll
    for (int nt = 0; nt < 2; ++nt) {
      #pragma unroll
      for (int j = 0; j < 4; ++j)
        bfr[nt][j] = f2bf(W[(k0 + quad * 4 + j) * U_ + n0 + nt * 16 + row16]);
    }
    #pragma unroll
    for (int mt = 0; mt < 2; ++mt)
      #pragma unroll
      for (int nt = 0; nt < 2; ++nt)
        acc[mt][nt] = __builtin_amdgcn_mfma_f32_16x16x16bf16_1k(
            af[mt], bfr[nt], acc[mt][nt], 0, 0, 0);
  }

  // C/D layout: col = lane&15, row = quad*4 + r   (verified mapping)
  #pragma unroll
  for (int nt = 0; nt < 2; ++nt) {
    float bv = bias[n0 + nt * 16 + row16];
    #pragma unroll
    for (int mt = 0; mt < 2; ++mt)
      #pragma unroll
      for (int r = 0; r < 4; ++r)
        S[(m0 + mt * 16 + quad * 4 + r) * U_ + n0 + nt * 16 + row16] =
            acc[mt][nt][r] + bv;
  }
}

// ---- K2: fused tanh-score + softmax + context, workgroup = (b, 8 q's) ----
__global__ __launch_bounds__(256) void k_attn(
    const float* __restrict__ s1, const float* __restrict__ s2,
    const float* __restrict__ Vw, const float* __restrict__ values,
    float* __restrict__ out_ctx, float* __restrict__ out_w)
{
  __shared__ float s1s[8 * U_];        // 8 KB
  __shared__ float s2c[32 * 260];      // 33.3 KB, +4 pad keeps f4 reads conflict-free
  __shared__ float vws[U_];            // 1 KB
  __shared__ float scores[8 * SV_];    // 4 KB (holds weights after softmax)
  __shared__ float red[4];

  const int tid  = threadIdx.x;
  const int lane = tid & 63;
  const int wid  = tid >> 6;
  const int b    = blockIdx.y;
  const int q0   = blockIdx.x * 8;

  // stage s1 rows (8 x 256 fp32) + Vw
  {
    int fi = tid;
    #pragma unroll
    for (int i = 0; i < 2; ++i, fi += 256) {
      int q = fi >> 6, uu = fi & 63;
      *(f32x4*)&s1s[q * U_ + uu * 4] =
          *(const f32x4*)&s1[(b * SQ_ + q0 + q) * U_ + uu * 4];
    }
  }
  vws[tid] = Vw[tid];
  __syncthreads();

  // Svw = sum(Vw): block reduce
  float sp = vws[tid];
  #pragma unroll
  for (int o = 32; o; o >>= 1) sp += __shfl_xor(sp, o);
  if (lane == 0) red[wid] = sp;
  __syncthreads();
  const float Svw = red[0] + red[1] + red[2] + red[3];

  const int qi = tid >> 5;   // 0..7
  const int v2 = tid & 31;   // 0..31

  for (int vc = 0; vc < 4; ++vc) {
    __syncthreads();
    // stage s2 chunk: rows vc*32 .. vc*32+31
    {
      int fi = tid;
      #pragma unroll
      for (int i = 0; i < 8; ++i, fi += 256) {
        int v = fi >> 6, uu = fi & 63;
        *(f32x4*)&s2c[v * 260 + uu * 4] =
            *(const f32x4*)&s2[(b * SV_ + vc * 32 + v) * U_ + uu * 4];
      }
    }
    __syncthreads();

    float acc = 0.f;  // sum of vw_u * 1/(1+e^{2x})
    const f32x4* a4 = (const f32x4*)&s1s[qi * U_];
    const f32x4* p4 = (const f32x4*)&s2c[v2 * 260];
    const f32x4* w4 = (const f32x4*)vws;
    #pragma unroll 8
    for (int uu = 0; uu < 64; ++uu) {
      f32x4 a = a4[uu], sv = p4[uu], w = w4[uu];
      #pragma unroll
      for (int e = 0; e < 4; ++e) {
        float x = a[e] + sv[e];
        float t = __expf(x + x);
        float r = __fdividef(1.f, 1.f + t);
        acc = fmaf(w[e], r, acc);
      }
    }
    // tanh = 1 - 2r  ->  score = Svw - 2*acc   (Vb dropped: softmax shift-invariant)
    scores[qi * SV_ + vc * 32 + v2] = Svw - 2.f * acc;
  }
  __syncthreads();

  // softmax over v (128) — wave wid handles q = 2*wid, 2*wid+1
  #pragma unroll
  for (int qq = wid * 2; qq <= wid * 2 + 1; ++qq) {
    float x0 = scores[qq * SV_ + lane];
    float x1 = scores[qq * SV_ + lane + 64];
    float m = fmaxf(x0, x1);
    #pragma unroll
    for (int o = 32; o; o >>= 1) m = fmaxf(m, __shfl_xor(m, o));
    float e0 = __expf(x0 - m), e1 = __expf(x1 - m);
    float s = e0 + e1;
    #pragma unroll
    for (int o = 32; o; o >>= 1) s += __shfl_xor(s, o);
    float inv = __fdividef(1.f, s);
    e0 *= inv; e1 *= inv;
    scores[qq * SV_ + lane] = e0;
    scores[qq * SV_ + lane + 64] = e1;
    int wbase = (b * SQ_ + q0 + qq) * SV_;
    out_w[wbase + lane] = e0;
    out_w[wbase + lane + 64] = e1;
  }
  __syncthreads();

  // context[q][d] = sum_v w[q][v] * values[b,v,d]; thread owns d = tid, tid+256
  float c[8][2];
  #pragma unroll
  for (int q = 0; q < 8; ++q) { c[q][0] = 0.f; c[q][1] = 0.f; }
  const float* vbase = &values[b * SV_ * DV_];
  for (int v = 0; v < SV_; v += 4) {
    f32x4 wq[8];
    #pragma unroll
    for (int q = 0; q < 8; ++q) wq[q] = *(const f32x4*)&scores[q * SV_ + v];
    #pragma unroll
    for (int j = 0; j < 4; ++j) {
      float va  = vbase[(v + j) * DV_ + tid];
      float vb2 = vbase[(v + j) * DV_ + tid + 256];
      #pragma unroll
      for (int q = 0; q < 8; ++q) {
        c[q][0] = fmaf(wq[q][j], va,  c[q][0]);
        c[q][1] = fmaf(wq[q][j], vb2, c[q][1]);
      }
    }
  }
  #pragma unroll
  for (int q = 0; q < 8; ++q) {
    int obase = (b * SQ_ + q0 + q) * DV_;
    out_ctx[obase + tid]       = c[q][0];
    out_ctx[obase + tid + 256] = c[q][1];
  }
}

extern "C" void kernel_launch(void* const* d_in, const int* in_sizes, int n_in,
                              void* d_out, int out_size, void* d_ws, size_t ws_size,
                              hipStream_t stream) {
  (void)in_sizes; (void)n_in; (void)out_size; (void)ws_size;
  const float* Q  = (const float*)d_in[0];
  const float* Vv = (const float*)d_in[1];
  const float* W1 = (const float*)d_in[2];
  const float* b1 = (const float*)d_in[3];
  const float* W2 = (const float*)d_in[4];
  const float* b2 = (const float*)d_in[5];
  const float* Vw = (const float*)d_in[6];
  // d_in[7] = Vb: softmax is shift-invariant -> unused

  float* out_ctx = (float*)d_out;                       // [16,128,512]
  float* out_w   = out_ctx + B_ * SQ_ * DV_;            // [16,128,128,1]

  float* s1 = (float*)d_ws;                             // [2048,256]
  float* s2 = s1 + 2048 * U_;                           // [2048,256]

  k_proj<<<dim3(32, 4, 2), 256, 0, stream>>>(Q, Vv, W1, b1, W2, b2, s1, s2);
  k_attn<<<dim3(SQ_ / 8, B_), 256, 0, stream>>>(s1, s2, Vw, Vv, out_ctx, out_w);
}

// Round 2
// 108.177 us; speedup vs baseline: 1.3390x; 1.3390x over previous
//
#include <hip/hip_runtime.h>

#define B_  16
#define SQ_ 128
#define SV_ 128
#define DQ_ 512
#define DV_ 512
#define U_  256

typedef float f32x4 __attribute__((ext_vector_type(4)));
typedef short s16x4 __attribute__((ext_vector_type(4)));

__device__ __forceinline__ short f2bf(float f) {
  unsigned u = __float_as_uint(f);
  u += 0x7fffu + ((u >> 16) & 1u);   // RNE to bf16
  return (short)(u >> 16);
}

// ---- K1: E = exp(2*(X@W + b))  (bf16 MFMA; wave = 32m x 16n; grid 32x8x2 = 512 blocks) ----
__global__ __launch_bounds__(256) void k_proj(
    const float* __restrict__ Q, const float* __restrict__ Vv,
    const float* __restrict__ W1, const float* __restrict__ b1,
    const float* __restrict__ W2, const float* __restrict__ b2,
    float* __restrict__ E1, float* __restrict__ E2)
{
  const int which = blockIdx.z;
  const float* __restrict__ X    = which ? Vv : Q;
  const float* __restrict__ W    = which ? W2 : W1;
  const float* __restrict__ bias = which ? b2 : b1;
  float* __restrict__ E          = which ? E2 : E1;

  const int lane  = threadIdx.x & 63;
  const int wid   = threadIdx.x >> 6;
  const int row16 = lane & 15;
  const int quad  = lane >> 4;

  const int m0 = blockIdx.x * 64 + (wid >> 1) * 32;
  const int n0 = blockIdx.y * 32 + (wid & 1) * 16;

  f32x4 acc[2];
  acc[0] = (f32x4){0.f,0.f,0.f,0.f};
  acc[1] = (f32x4){0.f,0.f,0.f,0.f};

  for (int k0 = 0; k0 < DQ_; k0 += 16) {
    s16x4 af[2], bfr;
    #pragma unroll
    for (int mt = 0; mt < 2; ++mt) {
      f32x4 av = *(const f32x4*)&X[(m0 + mt * 16 + row16) * DQ_ + k0 + quad * 4];
      af[mt][0] = f2bf(av[0]); af[mt][1] = f2bf(av[1]);
      af[mt][2] = f2bf(av[2]); af[mt][3] = f2bf(av[3]);
    }
    #pragma unroll
    for (int j = 0; j < 4; ++j)
      bfr[j] = f2bf(W[(k0 + quad * 4 + j) * U_ + n0 + row16]);
    #pragma unroll
    for (int mt = 0; mt < 2; ++mt)
      acc[mt] = __builtin_amdgcn_mfma_f32_16x16x16bf16_1k(af[mt], bfr, acc[mt], 0, 0, 0);
  }

  float bv = bias[n0 + row16];
  #pragma unroll
  for (int mt = 0; mt < 2; ++mt)
    #pragma unroll
    for (int r = 0; r < 4; ++r) {
      float s = acc[mt][r] + bv;
      E[(m0 + mt * 16 + quad * 4 + r) * U_ + n0 + row16] = __expf(2.0f * s);
    }
}

// ---- K2: score via E1*E2 product + paired-rcp, softmax, context ----
// 1024 threads; thread = (v = vh*32+v5, u-slice uh of 32); all 8 q in registers.
__global__ __launch_bounds__(1024) void k_attn(
    const float* __restrict__ E1, const float* __restrict__ E2,
    const float* __restrict__ Vw, const float* __restrict__ values,
    float* __restrict__ out_ctx, float* __restrict__ out_w)
{
  __shared__ float e1s[8 * U_];   // 8 KB
  __shared__ float vws[U_];       // 1 KB
  __shared__ float part[4096];    // 16 KB: u-partials -> scores/weights -> ctx partials
  __shared__ float red[8];

  const int tid  = threadIdx.x;
  const int lane = tid & 63;
  const int wid  = tid >> 6;
  const int b  = blockIdx.y;
  const int q0 = blockIdx.x * 8;

  if (tid < 512) {
    int q = tid >> 6, u4 = tid & 63;
    ((f32x4*)e1s)[q * 64 + u4] =
        *(const f32x4*)&E1[(b * SQ_ + q0 + q) * U_ + u4 * 4];
  }
  if (tid < 256) vws[tid] = Vw[tid];
  __syncthreads();

  if (wid == 0) {  // Svw = sum(Vw); Vb dropped (softmax shift-invariant)
    float s = vws[lane] + vws[lane + 64] + vws[lane + 128] + vws[lane + 192];
    #pragma unroll
    for (int o = 32; o; o >>= 1) s += __shfl_xor(s, o);
    if (lane == 0) red[0] = s;
  }

  const int v5 = tid & 31;
  const int uh = (tid >> 5) & 7;
  const int vh = tid >> 8;
  const int v  = vh * 32 + v5;

  f32x4 e2r[8];
  {
    const f32x4* e2p = (const f32x4*)&E2[(b * SV_ + v) * U_ + uh * 32];
    #pragma unroll
    for (int uq = 0; uq < 8; ++uq) e2r[uq] = e2p[uq];
  }
  const f32x4* e1v = (const f32x4*)e1s;
  const f32x4* wv4 = (const f32x4*)vws;

  float acc[8];
  #pragma unroll
  for (int q = 0; q < 8; ++q) acc[q] = 0.f;

  #pragma unroll
  for (int uq = 0; uq < 8; ++uq) {
    f32x4 e2 = e2r[uq];
    f32x4 w  = wv4[uh * 8 + uq];
    #pragma unroll
    for (int q = 0; q < 8; ++q) {
      f32x4 e1 = e1v[q * 64 + uh * 8 + uq];
      // w0/d0 + w1/d1 = (w0*d1 + w1*d0) * rcp(d0*d1)
      float d0 = fmaf(e1[0], e2[0], 1.0f);
      float d1 = fmaf(e1[1], e2[1], 1.0f);
      float rp = __builtin_amdgcn_rcpf(d0 * d1);
      float n  = fmaf(w[1], d0, w[0] * d1);
      acc[q] = fmaf(rp, n, acc[q]);
      float d2 = fmaf(e1[2], e2[2], 1.0f);
      float d3 = fmaf(e1[3], e2[3], 1.0f);
      float rp2 = __builtin_amdgcn_rcpf(d2 * d3);
      float n2  = fmaf(w[3], d2, w[2] * d3);
      acc[q] = fmaf(rp2, n2, acc[q]);
    }
  }

  // reduce over u-slices: shfl folds uh bit0; LDS folds uh bits [2:1]
  #pragma unroll
  for (int q = 0; q < 8; ++q) acc[q] += __shfl_xor(acc[q], 32);
  if (lane < 32) {
    int uhh = wid & 3;   // wid = vh*4 + uh[2:1]
    #pragma unroll
    for (int q = 0; q < 8; ++q) part[uhh * 1024 + q * 128 + v] = acc[q];
  }
  __syncthreads();

  {
    int q = tid >> 7, vv = tid & 127;
    float s = part[q * 128 + vv] + part[1024 + q * 128 + vv] +
              part[2048 + q * 128 + vv] + part[3072 + q * 128 + vv];
    part[q * 128 + vv] = red[0] - 2.0f * s;   // score = Svw - 2*sum(w/d)
  }
  __syncthreads();

  if (wid < 8) {  // softmax over 128 v, wave per q
    int q = wid;
    float x0 = part[q * 128 + lane], x1 = part[q * 128 + lane + 64];
    float m = fmaxf(x0, x1);
    #pragma unroll
    for (int o = 32; o; o >>= 1) m = fmaxf(m, __shfl_xor(m, o));
    float e0 = __expf(x0 - m), e1 = __expf(x1 - m);
    float ssum = e0 + e1;
    #pragma unroll
    for (int o = 32; o; o >>= 1) ssum += __shfl_xor(ssum, o);
    float inv = __fdividef(1.0f, ssum);
    e0 *= inv; e1 *= inv;
    part[q * 128 + lane] = e0;
    part[q * 128 + lane + 64] = e1;
    int wbase = (b * SQ_ + q0 + q) * SV_;
    out_w[wbase + lane] = e0;
    out_w[wbase + lane + 64] = e1;
  }
  __syncthreads();

  // context: thread owns d = tid&511, half of v (h); values read exactly once
  const int d = tid & 511;
  const int h = tid >> 9;
  float c[8];
  #pragma unroll
  for (int q = 0; q < 8; ++q) c[q] = 0.f;
  const float* vb = values + (size_t)(b * SV_ + h * 64) * DV_ + d;
  for (int vl = 0; vl < 64; vl += 4) {
    f32x4 wq[8];
    #pragma unroll
    for (int q = 0; q < 8; ++q)
      wq[q] = *(const f32x4*)&part[q * 128 + h * 64 + vl];
    #pragma unroll
    for (int j = 0; j < 4; ++j) {
      float val = vb[(vl + j) * DV_];
      #pragma unroll
      for (int q = 0; q < 8; ++q) c[q] = fmaf(wq[q][j], val, c[q]);
    }
  }
  __syncthreads();
  if (h == 1) {
    #pragma unroll
    for (int q = 0; q < 8; ++q) part[q * 512 + d] = c[q];
  }
  __syncthreads();
  if (h == 0) {
    #pragma unroll
    for (int q = 0; q < 8; ++q)
      out_ctx[(b * SQ_ + q0 + q) * DV_ + d] = c[q] + part[q * 512 + d];
  }
}

extern "C" void kernel_launch(void* const* d_in, const int* in_sizes, int n_in,
                              void* d_out, int out_size, void* d_ws, size_t ws_size,
                              hipStream_t stream) {
  (void)in_sizes; (void)n_in; (void)out_size; (void)ws_size;
  const float* Q  = (const float*)d_in[0];
  const float* Vv = (const float*)d_in[1];
  const float* W1 = (const float*)d_in[2];
  const float* b1 = (const float*)d_in[3];
  const float* W2 = (const float*)d_in[4];
  const float* b2 = (const float*)d_in[5];
  const float* Vw = (const float*)d_in[6];
  // d_in[7] = Vb: unused (softmax shift-invariant)

  float* out_ctx = (float*)d_out;                 // [16,128,512]
  float* out_w   = out_ctx + B_ * SQ_ * DV_;      // [16,128,128,1]

  float* E1 = (float*)d_ws;                       // [2048,256]
  float* E2 = E1 + 2048 * U_;                     // [2048,256]

  k_proj<<<dim3(32, 8, 2), 256, 0, stream>>>(Q, Vv, W1, b1, W2, b2, E1, E2);
  k_attn<<<dim3(SQ_ / 8, B_), 1024, 0, stream>>>(E1, E2, Vw, Vv, out_ctx, out_w);
}